// Round 1
// baseline (282.786 us; speedup 1.0000x reference)
//
#include <hip/hip_runtime.h>
#include <stdint.h>

// ---------------- workspace layout (bytes) ----------------
#define HIST1_BINS 8192
#define HIST2_BINS 262144
#define ABOVE_CAP  131072u
#define BIN_CAP    262144u

#define OFF_HIST1  0
#define OFF_META   32768
#define OFF_HIST2  65536
#define OFF_ABOVE  1114112
#define OFF_BIN    1638400
#define ZERO_BYTES 1114112   // hist1 + meta + hist2 all zeroed each call
// meta: [0]=b1 [1]=cnt_above_hist1 [2]=Tlow [3]=r [4]=tie_cutoff_idx
//       [5]=above_cnt [6]=bin_cnt [7]=k_total

#define TIE_CAP 4096

// Suffix (from-the-top) inclusive scan of a[0..255] in LDS. Caller must
// __syncthreads() after filling a[] and may read results after return.
__device__ inline void suffix_scan_256(uint32_t* a, int tid) {
  for (int off = 1; off < 256; off <<= 1) {
    uint32_t v = (tid + off < 256) ? a[tid + off] : 0u;
    __syncthreads();
    a[tid] += v;
    __syncthreads();
  }
}

// ---------------- K1: 13-bit histogram of |ranking| keys ----------------
__global__ void k1_hist(const uint4* __restrict__ r4, uint32_t n4,
                        uint32_t* __restrict__ hist1) {
  __shared__ uint32_t lh[HIST1_BINS];
  int tid = threadIdx.x;
  for (int i = tid; i < HIST1_BINS; i += blockDim.x) lh[i] = 0;
  __syncthreads();
  uint32_t stride = gridDim.x * blockDim.x;
  for (uint32_t i = blockIdx.x * blockDim.x + tid; i < n4; i += stride) {
    uint4 u = r4[i];
    atomicAdd(&lh[(u.x & 0x7fffffffu) >> 18], 1u);
    atomicAdd(&lh[(u.y & 0x7fffffffu) >> 18], 1u);
    atomicAdd(&lh[(u.z & 0x7fffffffu) >> 18], 1u);
    atomicAdd(&lh[(u.w & 0x7fffffffu) >> 18], 1u);
  }
  __syncthreads();
  for (int i = tid; i < HIST1_BINS; i += blockDim.x) {
    uint32_t v = lh[i];
    if (v) atomicAdd(&hist1[i], v);
  }
}

// ---------------- K2: find coarse bin b1 and count strictly above ----------------
__global__ void k2_scan1(const uint32_t* __restrict__ hist1,
                         uint32_t* __restrict__ meta,
                         const int* __restrict__ kptr) {
  __shared__ uint32_t a[256];
  __shared__ uint32_t s_chunk, s_base;
  int tid = threadIdx.x;
  uint32_t kt = (uint32_t)(*kptr) * 1024u;  // B = 1024 (fixed problem shape)
  uint32_t s = 0;
  for (int i = 0; i < 32; i++) s += hist1[tid * 32 + i];
  a[tid] = s;
  __syncthreads();
  suffix_scan_256(a, tid);
  {
    uint32_t incl = a[tid];
    uint32_t excl = (tid < 255) ? a[tid + 1] : 0u;
    if (excl < kt && incl >= kt) { s_chunk = (uint32_t)tid; s_base = excl; }
  }
  __syncthreads();
  uint32_t chunk = s_chunk, base = s_base;
  uint32_t v = (tid < 32) ? hist1[chunk * 32 + tid] : 0u;
  a[tid] = v;
  __syncthreads();
  suffix_scan_256(a, tid);
  {
    uint32_t incl = base + a[tid];
    uint32_t excl = base + ((tid < 255) ? a[tid + 1] : 0u);
    if (tid < 32 && excl < kt && incl >= kt) {
      meta[0] = chunk * 32u + (uint32_t)tid;
      meta[1] = excl;
      meta[7] = kt;
    }
  }
}

// ---------------- K3: compact candidates + fine histogram ----------------
__global__ void k3_compact(const uint4* __restrict__ r4, uint32_t n4,
                           uint32_t* __restrict__ meta, uint32_t* __restrict__ hist2,
                           uint32_t* __restrict__ above_list, uint2* __restrict__ bin_list) {
  __shared__ uint32_t sa[1024];
  __shared__ uint2 sb[1024];
  __shared__ uint32_t ca, cb, ba, bb;
  int tid = threadIdx.x;
  if (tid == 0) { ca = 0; cb = 0; }
  __syncthreads();
  uint32_t b1 = meta[0];
  uint32_t stride = gridDim.x * blockDim.x;
  for (uint32_t i = blockIdx.x * blockDim.x + tid; i < n4; i += stride) {
    uint4 u = r4[i];
    uint32_t keys[4];
    keys[0] = u.x & 0x7fffffffu;
    keys[1] = u.y & 0x7fffffffu;
    keys[2] = u.z & 0x7fffffffu;
    keys[3] = u.w & 0x7fffffffu;
#pragma unroll
    for (int l = 0; l < 4; l++) {
      uint32_t key = keys[l];
      uint32_t bin = key >> 18;
      if (bin < b1) continue;
      uint32_t idx = i * 4u + (uint32_t)l;
      if (bin > b1) {
        uint32_t p = atomicAdd(&ca, 1u);
        if (p < 1024u) sa[p] = idx;
        else { uint32_t g = atomicAdd(&meta[5], 1u); if (g < ABOVE_CAP) above_list[g] = idx; }
      } else {
        uint32_t low = key & 0x3ffffu;
        atomicAdd(&hist2[low], 1u);
        uint32_t p = atomicAdd(&cb, 1u);
        if (p < 1024u) { sb[p].x = idx; sb[p].y = low; }
        else {
          uint32_t g = atomicAdd(&meta[6], 1u);
          if (g < BIN_CAP) { bin_list[g].x = idx; bin_list[g].y = low; }
        }
      }
    }
  }
  __syncthreads();
  if (tid == 0) {
    ba = atomicAdd(&meta[5], (ca < 1024u) ? ca : 1024u);
    bb = atomicAdd(&meta[6], (cb < 1024u) ? cb : 1024u);
  }
  __syncthreads();
  uint32_t na = (ca < 1024u) ? ca : 1024u;
  uint32_t nb = (cb < 1024u) ? cb : 1024u;
  for (uint32_t p = tid; p < na; p += blockDim.x) {
    uint32_t g = ba + p; if (g < ABOVE_CAP) above_list[g] = sa[p];
  }
  for (uint32_t p = tid; p < nb; p += blockDim.x) {
    uint32_t g = bb + p; if (g < BIN_CAP) bin_list[g] = sb[p];
  }
}

// ---------------- K4: exact threshold (low 18 bits) ----------------
__global__ void k4_scan2(const uint32_t* __restrict__ hist2, uint32_t* __restrict__ meta) {
  __shared__ uint32_t a[256];
  __shared__ uint32_t s_c1, s_base1, s_c2, s_base2;
  int tid = threadIdx.x;
  uint32_t kt = meta[7];
  uint32_t base0 = meta[1];
  uint32_t s = 0;
  {
    const uint32_t* p = hist2 + (uint32_t)tid * 1024u;
    for (int i = 0; i < 1024; i++) s += p[i];
  }
  a[tid] = s;
  __syncthreads();
  suffix_scan_256(a, tid);
  {
    uint32_t incl = base0 + a[tid];
    uint32_t excl = base0 + ((tid < 255) ? a[tid + 1] : 0u);
    if (excl < kt && incl >= kt) { s_c1 = (uint32_t)tid; s_base1 = excl; }
  }
  __syncthreads();
  uint32_t c1 = s_c1, base1 = s_base1;
  uint32_t s2 = 0;
  {
    const uint32_t* p2 = hist2 + c1 * 1024u + (uint32_t)tid * 4u;
#pragma unroll
    for (int i = 0; i < 4; i++) s2 += p2[i];
  }
  __syncthreads();          // protect a[] reads above before overwrite
  a[tid] = s2;
  __syncthreads();
  suffix_scan_256(a, tid);
  {
    uint32_t incl = base1 + a[tid];
    uint32_t excl = base1 + ((tid < 255) ? a[tid + 1] : 0u);
    if (excl < kt && incl >= kt) { s_c2 = (uint32_t)tid; s_base2 = excl; }
  }
  __syncthreads();
  if (tid == 0) {
    uint32_t c2 = s_c2;
    uint32_t acc = s_base2;
    for (int j = 3; j >= 0; j--) {
      uint32_t bin = c1 * 1024u + c2 * 4u + (uint32_t)j;
      uint32_t h = hist2[bin];
      if (acc + h >= kt) { meta[2] = bin; meta[3] = kt - acc; break; }
      acc += h;
    }
  }
}

// ---------------- K5: tie-break at exact threshold (lowest indices first) ----------------
__global__ void k5_ties(const uint2* __restrict__ bin_list, uint32_t* __restrict__ meta) {
  __shared__ uint32_t tie[TIE_CAP];
  __shared__ uint32_t cnt;
  int tid = threadIdx.x;
  if (tid == 0) cnt = 0;
  __syncthreads();
  uint32_t Tlow = meta[2];
  uint32_t nb = meta[6]; if (nb > BIN_CAP) nb = BIN_CAP;
  for (uint32_t i = tid; i < nb; i += blockDim.x) {
    uint2 e = bin_list[i];
    if (e.y == Tlow) { uint32_t p = atomicAdd(&cnt, 1u); if (p < TIE_CAP) tie[p] = e.x; }
  }
  __syncthreads();
  uint32_t m = cnt; if (m > TIE_CAP) m = TIE_CAP;
  uint32_t r = meta[3];
  if (r >= m) { if (tid == 0) meta[4] = 0xffffffffu; return; }
  for (uint32_t t = tid; t < m; t += blockDim.x) {
    uint32_t v = tie[t];
    uint32_t rank = 0;
    for (uint32_t j = 0; j < m; j++) rank += (tie[j] < v) ? 1u : 0u;
    if (rank == r - 1u) meta[4] = v;   // r-th smallest tied index = cutoff
  }
}

// ---------------- K6: scatter selected x values into zeroed output ----------------
__global__ void k6_scatter(const float* __restrict__ x, float* __restrict__ out,
                           const uint32_t* __restrict__ meta,
                           const uint32_t* __restrict__ above_list,
                           const uint2* __restrict__ bin_list) {
  uint32_t na = meta[5]; if (na > ABOVE_CAP) na = ABOVE_CAP;
  uint32_t nb = meta[6]; if (nb > BIN_CAP) nb = BIN_CAP;
  uint32_t Tlow = meta[2], cutoff = meta[4];
  uint32_t total = na + nb;
  uint32_t stride = gridDim.x * blockDim.x;
  for (uint32_t i = blockIdx.x * blockDim.x + threadIdx.x; i < total; i += stride) {
    if (i < na) {
      uint32_t idx = above_list[i];
      out[idx] = x[idx];
    } else {
      uint2 e = bin_list[i - na];
      if (e.y > Tlow || (e.y == Tlow && e.x <= cutoff)) out[e.x] = x[e.x];
    }
  }
}

extern "C" void kernel_launch(void* const* d_in, const int* in_sizes, int n_in,
                              void* d_out, int out_size, void* d_ws, size_t ws_size,
                              hipStream_t stream) {
  const float* x    = (const float*)d_in[0];
  const float* rank = (const float*)d_in[1];
  const int*   kptr = (const int*)d_in[2];
  float* out = (float*)d_out;
  uint32_t n  = (uint32_t)in_sizes[0];   // 67,108,864 (divisible by 4)
  uint32_t n4 = n / 4u;

  char* ws = (char*)d_ws;
  uint32_t* hist1      = (uint32_t*)(ws + OFF_HIST1);
  uint32_t* meta       = (uint32_t*)(ws + OFF_META);
  uint32_t* hist2      = (uint32_t*)(ws + OFF_HIST2);
  uint32_t* above_list = (uint32_t*)(ws + OFF_ABOVE);
  uint2*    bin_list   = (uint2*)(ws + OFF_BIN);

  hipMemsetAsync(d_ws, 0, ZERO_BYTES, stream);
  hipMemsetAsync(d_out, 0, (size_t)out_size * sizeof(float), stream);

  k1_hist   <<<2048, 256, 0, stream>>>((const uint4*)rank, n4, hist1);
  k2_scan1  <<<1,    256, 0, stream>>>(hist1, meta, kptr);
  k3_compact<<<2048, 256, 0, stream>>>((const uint4*)rank, n4, meta, hist2,
                                       above_list, bin_list);
  k4_scan2  <<<1,    256, 0, stream>>>(hist2, meta);
  k5_ties   <<<1,    256, 0, stream>>>(bin_list, meta);
  k6_scatter<<<512,  256, 0, stream>>>(x, out, meta, above_list, bin_list);
}

// Round 3
// 235.355 us; speedup vs baseline: 1.2015x; 1.2015x over previous
//
#include <hip/hip_runtime.h>
#include <stdint.h>

typedef uint32_t u32x4 __attribute__((ext_vector_type(4)));

// ---------------- workspace layout (bytes) ----------------
#define HIST1_BINS 8192
#define ABOVE_CAP  131072u
#define BIN_CAP    262144u

#define OFF_HIST1  0
#define OFF_META   32768
#define OFF_ABOVE  65536
#define OFF_BIN    589824
#define ZERO_BYTES 36864   // hist1 + meta
// meta: [0]=b1 [1]=cnt_above_hist1 [2]=Tlow [3]=rem [4]=tie_cutoff_idx
//       [5]=above_cnt [6]=bin_cnt [7]=k_total

#define TIE_CAP 4096

// Suffix (from-the-top) inclusive scan of a[0..255] in LDS.
__device__ inline void suffix_scan_256(uint32_t* a, int tid) {
  for (int off = 1; off < 256; off <<= 1) {
    uint32_t v = (tid + off < 256) ? a[tid + off] : 0u;
    __syncthreads();
    a[tid] += v;
    __syncthreads();
  }
}

// ---------------- K1: 13-bit histogram of |ranking| + zero the output ----------------
__global__ void k1_hist_zero(const uint4* __restrict__ r4, u32x4* __restrict__ out4,
                             uint32_t n4, uint32_t* __restrict__ hist1) {
  __shared__ uint32_t lh[HIST1_BINS];
  int tid = threadIdx.x;
  for (int i = tid; i < HIST1_BINS; i += blockDim.x) lh[i] = 0;
  __syncthreads();
  const u32x4 z = {0u, 0u, 0u, 0u};
  uint32_t stride = gridDim.x * blockDim.x;
  for (uint32_t i = blockIdx.x * blockDim.x + tid; i < n4; i += stride) {
    uint4 u = r4[i];
    __builtin_nontemporal_store(z, &out4[i]);
    atomicAdd(&lh[(u.x & 0x7fffffffu) >> 18], 1u);
    atomicAdd(&lh[(u.y & 0x7fffffffu) >> 18], 1u);
    atomicAdd(&lh[(u.z & 0x7fffffffu) >> 18], 1u);
    atomicAdd(&lh[(u.w & 0x7fffffffu) >> 18], 1u);
  }
  __syncthreads();
  for (int i = tid; i < HIST1_BINS; i += blockDim.x) {
    uint32_t v = lh[i];
    if (v) atomicAdd(&hist1[i], v);
  }
}

// ---------------- K2: find coarse bin b1 and count strictly above ----------------
__global__ void k2_scan1(const uint32_t* __restrict__ hist1,
                         uint32_t* __restrict__ meta,
                         const int* __restrict__ kptr) {
  __shared__ uint32_t a[256];
  __shared__ uint32_t s_chunk, s_base;
  int tid = threadIdx.x;
  uint32_t kt = (uint32_t)(*kptr) * 1024u;  // B = 1024 (fixed problem shape)
  uint32_t s = 0;
  for (int i = 0; i < 32; i++) s += hist1[tid * 32 + i];
  a[tid] = s;
  __syncthreads();
  suffix_scan_256(a, tid);
  {
    uint32_t incl = a[tid];
    uint32_t excl = (tid < 255) ? a[tid + 1] : 0u;
    if (excl < kt && incl >= kt) { s_chunk = (uint32_t)tid; s_base = excl; }
  }
  __syncthreads();
  uint32_t chunk = s_chunk, base = s_base;
  uint32_t v = (tid < 32) ? hist1[chunk * 32 + tid] : 0u;
  a[tid] = v;
  __syncthreads();
  suffix_scan_256(a, tid);
  {
    uint32_t incl = base + a[tid];
    uint32_t excl = base + ((tid < 255) ? a[tid + 1] : 0u);
    if (tid < 32 && excl < kt && incl >= kt) {
      meta[0] = chunk * 32u + (uint32_t)tid;
      meta[1] = excl;
      meta[7] = kt;
    }
  }
}

// ---------------- K3: compact candidates (bin > b1 and bin == b1) ----------------
__global__ void k3_compact(const uint4* __restrict__ r4, uint32_t n4,
                           uint32_t* __restrict__ meta,
                           uint32_t* __restrict__ above_list, uint2* __restrict__ bin_list) {
  __shared__ uint32_t sa[1024];
  __shared__ uint2 sb[1024];
  __shared__ uint32_t ca, cb, ba, bb;
  int tid = threadIdx.x;
  if (tid == 0) { ca = 0; cb = 0; }
  __syncthreads();
  uint32_t b1 = meta[0];
  uint32_t stride = gridDim.x * blockDim.x;
  for (uint32_t i = blockIdx.x * blockDim.x + tid; i < n4; i += stride) {
    uint4 u = r4[i];
    uint32_t keys[4];
    keys[0] = u.x & 0x7fffffffu;
    keys[1] = u.y & 0x7fffffffu;
    keys[2] = u.z & 0x7fffffffu;
    keys[3] = u.w & 0x7fffffffu;
#pragma unroll
    for (int l = 0; l < 4; l++) {
      uint32_t key = keys[l];
      uint32_t bin = key >> 18;
      if (bin < b1) continue;
      uint32_t idx = i * 4u + (uint32_t)l;
      if (bin > b1) {
        uint32_t p = atomicAdd(&ca, 1u);
        if (p < 1024u) sa[p] = idx;
        else { uint32_t g = atomicAdd(&meta[5], 1u); if (g < ABOVE_CAP) above_list[g] = idx; }
      } else {
        uint32_t low = key & 0x3ffffu;
        uint32_t p = atomicAdd(&cb, 1u);
        if (p < 1024u) { sb[p].x = idx; sb[p].y = low; }
        else {
          uint32_t g = atomicAdd(&meta[6], 1u);
          if (g < BIN_CAP) { bin_list[g].x = idx; bin_list[g].y = low; }
        }
      }
    }
  }
  __syncthreads();
  if (tid == 0) {
    ba = atomicAdd(&meta[5], (ca < 1024u) ? ca : 1024u);
    bb = atomicAdd(&meta[6], (cb < 1024u) ? cb : 1024u);
  }
  __syncthreads();
  uint32_t na = (ca < 1024u) ? ca : 1024u;
  uint32_t nb = (cb < 1024u) ? cb : 1024u;
  for (uint32_t p = tid; p < na; p += blockDim.x) {
    uint32_t g = ba + p; if (g < ABOVE_CAP) above_list[g] = sa[p];
  }
  for (uint32_t p = tid; p < nb; p += blockDim.x) {
    uint32_t g = bb + p; if (g < BIN_CAP) bin_list[g] = sb[p];
  }
}

// ---------------- K4: exact threshold + tie cutoff, single block over bin_list ----------------
__global__ void k4_select(const uint2* __restrict__ bin_list, uint32_t* __restrict__ meta) {
  __shared__ uint32_t a[256];
  __shared__ uint32_t h256[256];
  __shared__ uint32_t h1k[1024];
  __shared__ uint32_t tie[TIE_CAP];
  __shared__ uint32_t tiecnt;
  __shared__ uint32_t s_c1, s_base1, s_c2, s_base2;
  int tid = threadIdx.x;
  uint32_t kt = meta[7];
  uint32_t base0 = meta[1];
  uint32_t r = kt - base0;                   // rank (1-based) within bin b1
  uint32_t nb = meta[6]; if (nb > BIN_CAP) nb = BIN_CAP;

  h256[tid] = 0;
  for (int i = tid; i < 1024; i += 256) h1k[i] = 0;
  if (tid == 0) tiecnt = 0;
  __syncthreads();

  // stage 1: 256-bin histogram of low18 >> 10
  for (uint32_t i = tid; i < nb; i += 256u)
    atomicAdd(&h256[bin_list[i].y >> 10], 1u);
  __syncthreads();
  a[tid] = h256[tid];
  __syncthreads();
  suffix_scan_256(a, tid);
  {
    uint32_t incl = a[tid];
    uint32_t excl = (tid < 255) ? a[tid + 1] : 0u;
    if (excl < r && incl >= r) { s_c1 = (uint32_t)tid; s_base1 = excl; }
  }
  __syncthreads();
  uint32_t c1 = s_c1, base1 = s_base1;

  // stage 2: 1024-bin histogram of low10 within sub-bin c1
  for (uint32_t i = tid; i < nb; i += 256u) {
    uint2 e = bin_list[i];
    if ((e.y >> 10) == c1) atomicAdd(&h1k[e.y & 1023u], 1u);
  }
  __syncthreads();
  uint32_t r1 = r - base1;
  uint32_t s4 = h1k[tid * 4] + h1k[tid * 4 + 1] + h1k[tid * 4 + 2] + h1k[tid * 4 + 3];
  a[tid] = s4;
  __syncthreads();
  suffix_scan_256(a, tid);
  {
    uint32_t incl = a[tid];
    uint32_t excl = (tid < 255) ? a[tid + 1] : 0u;
    if (excl < r1 && incl >= r1) { s_c2 = (uint32_t)tid; s_base2 = excl; }
  }
  __syncthreads();
  if (tid == 0) {
    uint32_t c2 = s_c2;
    uint32_t acc = s_base2;
    for (int j = 3; j >= 0; j--) {
      uint32_t low10 = c2 * 4u + (uint32_t)j;
      uint32_t h = h1k[low10];
      if (acc + h >= r1) { meta[2] = (c1 << 10) | low10; meta[3] = r1 - acc; break; }
      acc += h;
    }
  }
  __syncthreads();
  uint32_t Tlow = meta[2], rem = meta[3];

  // tie-break: keep the `rem` lowest flat indices among entries with key == Tlow
  for (uint32_t i = tid; i < nb; i += 256u) {
    uint2 e = bin_list[i];
    if (e.y == Tlow) { uint32_t p = atomicAdd(&tiecnt, 1u); if (p < TIE_CAP) tie[p] = e.x; }
  }
  __syncthreads();
  uint32_t m = tiecnt; if (m > TIE_CAP) m = TIE_CAP;
  if (rem >= m) { if (tid == 0) meta[4] = 0xffffffffu; return; }
  for (uint32_t t = tid; t < m; t += 256u) {
    uint32_t v = tie[t];
    uint32_t rank = 0;
    for (uint32_t j = 0; j < m; j++) rank += (tie[j] < v) ? 1u : 0u;
    if (rank == rem - 1u) meta[4] = v;   // rem-th smallest tied index = cutoff
  }
}

// ---------------- K6: scatter selected x values into zeroed output ----------------
__global__ void k6_scatter(const float* __restrict__ x, float* __restrict__ out,
                           const uint32_t* __restrict__ meta,
                           const uint32_t* __restrict__ above_list,
                           const uint2* __restrict__ bin_list) {
  uint32_t na = meta[5]; if (na > ABOVE_CAP) na = ABOVE_CAP;
  uint32_t nb = meta[6]; if (nb > BIN_CAP) nb = BIN_CAP;
  uint32_t Tlow = meta[2], cutoff = meta[4];
  uint32_t total = na + nb;
  uint32_t stride = gridDim.x * blockDim.x;
  for (uint32_t i = blockIdx.x * blockDim.x + threadIdx.x; i < total; i += stride) {
    if (i < na) {
      uint32_t idx = above_list[i];
      out[idx] = x[idx];
    } else {
      uint2 e = bin_list[i - na];
      if (e.y > Tlow || (e.y == Tlow && e.x <= cutoff)) out[e.x] = x[e.x];
    }
  }
}

extern "C" void kernel_launch(void* const* d_in, const int* in_sizes, int n_in,
                              void* d_out, int out_size, void* d_ws, size_t ws_size,
                              hipStream_t stream) {
  const float* x    = (const float*)d_in[0];
  const float* rank = (const float*)d_in[1];
  const int*   kptr = (const int*)d_in[2];
  float* out = (float*)d_out;
  uint32_t n  = (uint32_t)in_sizes[0];   // 67,108,864 (divisible by 4)
  uint32_t n4 = n / 4u;

  char* ws = (char*)d_ws;
  uint32_t* hist1      = (uint32_t*)(ws + OFF_HIST1);
  uint32_t* meta       = (uint32_t*)(ws + OFF_META);
  uint32_t* above_list = (uint32_t*)(ws + OFF_ABOVE);
  uint2*    bin_list   = (uint2*)(ws + OFF_BIN);

  (void)hipMemsetAsync(d_ws, 0, ZERO_BYTES, stream);

  k1_hist_zero<<<2048, 256, 0, stream>>>((const uint4*)rank, (u32x4*)out, n4, hist1);
  k2_scan1    <<<1,    256, 0, stream>>>(hist1, meta, kptr);
  k3_compact  <<<2048, 256, 0, stream>>>((const uint4*)rank, n4, meta,
                                         above_list, bin_list);
  k4_select   <<<1,    256, 0, stream>>>(bin_list, meta);
  k6_scatter  <<<512,  256, 0, stream>>>(x, out, meta, above_list, bin_list);
}